// Round 11
// baseline (217.770 us; speedup 1.0000x reference)
//
#include <hip/hip_runtime.h>

// FullFixedTimeCausalConstructiveAttention — MFMA flash, NO LDS, NO BARRIERS.
// B=8, L=1024, H=8, E=64, HIST=512. Inputs fp32, output fp32.
// Layout: (b, l, h, e) row-major; per-(b,h) row stride = H*E = 512 floats.
//
// R11 = R9 with plain __launch_bounds__(256) (no forced 4 waves/EU): avoids
// forced VGPR spill (est. demand ~150-170 > 128 cap the old bound implied).
// Waves are barrier-free/independent, so occupancy-by-VGPR (~12 waves/CU)
// still gives more independent streams than the phase-locked R4 baseline.
//
// Discriminating experiment vs the phase-lock theory: sigma-permuted K rows +
// swapped-PV A-fragment layout make BOTH operand fragments directly
// global-loadable with 100% line utilization:
//   K frag: 16 float4 loads/iter (16KB, each line once)
//   V frag: v0[j] = V[kbase+8lq+j][16nb+ln] -> 64 dword loads/iter, each hits
//           4 fully-consumed 64B lines (j = consecutive rows; the "transpose"
//           falls out of the fragment layout). 16KB, each line once per iter.
// zdiag in-register (red4sum gives each lane its own q-row's diag — no LDS).
// Same math bit-for-bit as R4 ((f16) casts, same MFMA order): no absmax risk.
#define LL   1024
#define HH   8
#define EE   64

#define SCALE2 0.18033688011112043f   // (1/sqrt(64)) * log2(e)

typedef _Float16 f16;
typedef _Float16 v8h  __attribute__((ext_vector_type(8)));
typedef _Float16 h2   __attribute__((ext_vector_type(2)));
typedef float    v4f  __attribute__((ext_vector_type(4)));
typedef int      v2i  __attribute__((ext_vector_type(2)));

__device__ __forceinline__ float fexp2(float x) {
#if __has_builtin(__builtin_amdgcn_exp2f)
  return __builtin_amdgcn_exp2f(x);
#else
  return __expf(x * 0.6931471805599453f);
#endif
}

__device__ __forceinline__ h2 pkh2(float a, float b) {
#if __has_builtin(__builtin_amdgcn_cvt_pkrtz)
  return __builtin_bit_cast(h2, __builtin_amdgcn_cvt_pkrtz(a, b));
#else
  h2 r; r[0] = (f16)a; r[1] = (f16)b; return r;
#endif
}

// Reduce across the 4 lane-quarters (lanes ln, ln+16, ln+32, ln+48).
__device__ __forceinline__ float red4max(float x) {
#if __has_builtin(__builtin_amdgcn_permlane16_swap) && __has_builtin(__builtin_amdgcn_permlane32_swap)
  int xi = __float_as_int(x);
  v2i a = __builtin_amdgcn_permlane16_swap(xi, xi, false, false);
  float m = fmaxf(__int_as_float(a.x), __int_as_float(a.y));
  int mi = __float_as_int(m);
  v2i b = __builtin_amdgcn_permlane32_swap(mi, mi, false, false);
  return fmaxf(__int_as_float(b.x), __int_as_float(b.y));
#else
  x = fmaxf(x, __shfl_xor(x, 16));
  return fmaxf(x, __shfl_xor(x, 32));
#endif
}

__device__ __forceinline__ float red4sum(float x) {
#if __has_builtin(__builtin_amdgcn_permlane16_swap) && __has_builtin(__builtin_amdgcn_permlane32_swap)
  int xi = __float_as_int(x);
  v2i a = __builtin_amdgcn_permlane16_swap(xi, xi, false, false);
  float s = __int_as_float(a.x) + __int_as_float(a.y);
  int si = __float_as_int(s);
  v2i b = __builtin_amdgcn_permlane32_swap(si, si, false, false);
  return __int_as_float(b.x) + __int_as_float(b.y);
#else
  x += __shfl_xor(x, 16);
  return x + __shfl_xor(x, 32);
#endif
}

__device__ __forceinline__ void load16f(const float* __restrict__ p, float* __restrict__ f) {
  const float4* p4 = reinterpret_cast<const float4*>(p);
  float4 a = p4[0], b = p4[1], c = p4[2], d = p4[3];
  f[0]=a.x;  f[1]=a.y;  f[2]=a.z;  f[3]=a.w;
  f[4]=b.x;  f[5]=b.y;  f[6]=b.z;  f[7]=b.w;
  f[8]=c.x;  f[9]=c.y;  f[10]=c.z; f[11]=c.w;
  f[12]=d.x; f[13]=d.y; f[14]=d.z; f[15]=d.w;
}

__device__ __forceinline__ void load8f(const float* __restrict__ p, float* __restrict__ f) {
  const float4* p4 = reinterpret_cast<const float4*>(p);
  float4 a = p4[0], b = p4[1];
  f[0]=a.x; f[1]=a.y; f[2]=a.z; f[3]=a.w;
  f[4]=b.x; f[5]=b.y; f[6]=b.z; f[7]=b.w;
}

extern "C" __global__ __launch_bounds__(256)
void ftcca_nolds(const float* __restrict__ Q,  const float* __restrict__ K,
                 const float* __restrict__ V,  const float* __restrict__ Qd,
                 const float* __restrict__ Kd, const float* __restrict__ Vd,
                 float* __restrict__ out)
{
  // bh = blockIdx & 63: all 16 q-tile blocks of one (b,h) land on one XCD (L2 share)
  const int bh  = blockIdx.x & 63;
  const int a   = blockIdx.x >> 6;      // 0..15
  const int qt  = 15 - a;               // big K-ranges first
  const bool drawn = (qt >= 8);         // l >= 512 -> drawn rows
  const int b   = bh >> 3, h = bh & 7;
  const int t   = threadIdx.x;
  const int w    = t >> 6;              // q sub-tile (waves are fully independent)
  const int lane = t & 63;
  const int ln   = lane & 15;
  const int lq   = lane >> 4;

  const size_t base = ((size_t)b * LL * HH + h) * EE;
  const int ROWF = HH * EE;             // 512

  // sigma tables: K-frag read rows (indexed by ln) and owned-k bases (indexed by lq)
  const int q2 = ln >> 2;
  int rk[4], kb[4];
  rk[0] = ln + ((q2 + 1) >> 1) * 8;     // off[0] = {0,8,8,16}
  rk[1] = ln + 4 + (q2 >> 1) * 8;       // off[1] = {4,4,12,12}
  rk[2] = rk[0] + 32;
  rk[3] = rk[1] + 32;
  kb[0] = 4 * lq + ((lq + 1) >> 1) * 8;
  kb[1] = 4 * lq + 4 + (lq >> 1) * 8;
  kb[2] = kb[0] + 32;
  kb[3] = kb[1] + 32;

  const int qlocal = w * 16 + ln;

  // ---- zdiag in-register (drawn only): every lane ends with its own q-row's diag ----
  float zdq = 0.f;
  if (drawn) {
    const int qrow = qt * 64 + qlocal;
    float fq[16], fk[16];
    load16f(Qd + base + (size_t)qrow * ROWF + 16 * lq, fq);
    load16f(Kd + base + (size_t)qrow * ROWF + 16 * lq, fk);
    float pa = 0.f;
#pragma unroll
    for (int ii = 0; ii < 16; ++ii) pa += fq[ii] * fk[ii];
    zdq = SCALE2 * red4sum(pa);         // all lq quarters -> full 64-dim dot
  }

  // ---- Q fragments (B-operand of QK^T: free-dim=ln, k=32c+8lq+j) ----
  const float* qsrc = drawn ? Qd : Q;
  v8h qf[2];
  {
    const float* pq = qsrc + base + (size_t)(qt * 64 + qlocal) * ROWF;
#pragma unroll
    for (int c = 0; c < 2; ++c) {
      float x[8];
      load8f(pq + 32 * c + 8 * lq, x);
#pragma unroll
      for (int j = 0; j < 8; ++j) qf[c][j] = (f16)x[j];
    }
  }

  v4f   o[4];
#pragma unroll
  for (int nb = 0; nb < 4; ++nb) o[nb] = (v4f){0, 0, 0, 0};
  float m = -1e30f, l = 0.f, pd = 0.f;

  for (int i = 0; i <= qt; ++i) {
    const int kbase = i * 64;
    const bool dt = (i == qt);

    // ---- K fragments direct from global (16x float4, each 64B line once) ----
    v8h k0f[4], k1f[4];
#pragma unroll
    for (int nb = 0; nb < 4; ++nb) {
      const float* kr = K + base + (size_t)(kbase + rk[nb]) * ROWF;
      float x0[8], x1[8];
      load8f(kr + 8 * lq, x0);
      load8f(kr + 32 + 8 * lq, x1);
#pragma unroll
      for (int j = 0; j < 8; ++j) { k0f[nb][j] = (f16)x0[j]; k1f[nb][j] = (f16)x1[j]; }
    }

    // ---- S^T = K Q^T ----
    v4f S[4];
#pragma unroll
    for (int nb = 0; nb < 4; ++nb) {
      v4f acc = (v4f){0.f, 0.f, 0.f, 0.f};
      acc = __builtin_amdgcn_mfma_f32_16x16x32_f16(k0f[nb], qf[0], acc, 0, 0, 0);
      acc = __builtin_amdgcn_mfma_f32_16x16x32_f16(k1f[nb], qf[1], acc, 0, 0, 0);
      S[nb] = acc;
    }

    // ---- V fragments direct from global (issued here; land under softmax) ----
    // v0[j] = V[kbase+8lq+j][16nb+ln], v1[j] = V[kbase+32+8lq+j][16nb+ln]
    v8h vf0[4], vf1[4];
#pragma unroll
    for (int nb = 0; nb < 4; ++nb) {
      const float* vc = V + base + (size_t)(kbase + 8 * lq) * ROWF + 16 * nb + ln;
      float y0[8], y1[8];
#pragma unroll
      for (int j = 0; j < 8; ++j) y0[j] = vc[(size_t)j * ROWF];
#pragma unroll
      for (int j = 0; j < 8; ++j) y1[j] = vc[(size_t)(32 + j) * ROWF];
#pragma unroll
      for (int j = 0; j < 8; ++j) { vf0[nb][j] = (f16)y0[j]; vf1[nb][j] = (f16)y1[j]; }
    }

    // ---- mask + online softmax (q = ln lane-local) ----
    float z[4][4];
#pragma unroll
    for (int nb = 0; nb < 4; ++nb)
#pragma unroll
      for (int r = 0; r < 4; ++r) z[nb][r] = S[nb][r] * SCALE2;

    if (dt) {
#pragma unroll
      for (int nb = 0; nb < 4; ++nb) {
#pragma unroll
        for (int r = 0; r < 4; ++r) {
          const int kl = kb[nb] + r;             // sigma(nb, 4lq+r)
          if (kl > qlocal)                 z[nb][r] = -1e30f;  // causal mask
          else if (drawn && kl == qlocal)  z[nb][r] = zdq;     // diag replace
        }
      }
    }

    float a0 = fmaxf(fmaxf(z[0][0], z[0][1]), fmaxf(z[0][2], z[0][3]));
    float a1 = fmaxf(fmaxf(z[1][0], z[1][1]), fmaxf(z[1][2], z[1][3]));
    float a2 = fmaxf(fmaxf(z[2][0], z[2][1]), fmaxf(z[2][2], z[2][3]));
    float a3 = fmaxf(fmaxf(z[3][0], z[3][1]), fmaxf(z[3][2], z[3][3]));
    const float mx = red4max(fmaxf(fmaxf(a0, a1), fmaxf(a2, a3)));

    const float mn = fmaxf(m, mx);
    const float al = fexp2(m - mn);
    m = mn;

    float p[4][4], rsum = 0.f, pdl = 0.f;
#pragma unroll
    for (int nb = 0; nb < 4; ++nb) {
#pragma unroll
      for (int r = 0; r < 4; ++r) {
        const float pv = fexp2(z[nb][r] - mn);
        p[nb][r] = pv;
        rsum += pv;
        if (dt && drawn && (kb[nb] + r) == qlocal) pdl = pv;
      }
    }
    rsum = red4sum(rsum);
    if (dt && drawn) pd = red4sum(pdl);  // diag tile is last: no later rescale
    l = l * al + rsum;
#pragma unroll
    for (int nb = 0; nb < 4; ++nb)
#pragma unroll
      for (int r = 0; r < 4; ++r) o[nb][r] *= al;   // per-lane scalar rescale

    // ---- P -> B-fragment in-register (sigma: owned pairs == needed k-layout) ----
    h2 wq[4][2];
#pragma unroll
    for (int nb = 0; nb < 4; ++nb) {
      wq[nb][0] = pkh2(p[nb][0], p[nb][1]);
      wq[nb][1] = pkh2(p[nb][2], p[nb][3]);
    }
    const bool swp = (lq & 1);
    union U8 { v8h v; h2 h[4]; } A0, A1;
    A0.h[0] = swp ? wq[1][0] : wq[0][0];
    A0.h[1] = swp ? wq[1][1] : wq[0][1];
    A0.h[2] = swp ? wq[0][0] : wq[1][0];
    A0.h[3] = swp ? wq[0][1] : wq[1][1];
    A1.h[0] = swp ? wq[3][0] : wq[2][0];
    A1.h[1] = swp ? wq[3][1] : wq[2][1];
    A1.h[2] = swp ? wq[2][0] : wq[3][0];
    A1.h[3] = swp ? wq[2][1] : wq[3][1];

    // ---- O^T += V^T P^T ----
#pragma unroll
    for (int nb = 0; nb < 4; ++nb) {
      o[nb] = __builtin_amdgcn_mfma_f32_16x16x32_f16(vf0[nb], A0.v, o[nb], 0, 0, 0);
      o[nb] = __builtin_amdgcn_mfma_f32_16x16x32_f16(vf1[nb], A1.v, o[nb], 0, 0, 0);
    }
  }

  // ---- epilogue: O^T store — per-lane scalars, float4 per nb ----
  const float inv = 1.f / l;
  const float pdinv = pd * inv;
  const int lrow = qt * 64 + qlocal;

#pragma unroll
  for (int nb = 0; nb < 4; ++nb) {
    const int d0 = nb * 16 + lq * 4;
    const size_t g = base + (size_t)lrow * ROWF + d0;
    float4 o4;
    o4.x = o[nb][0] * inv;
    o4.y = o[nb][1] * inv;
    o4.z = o[nb][2] * inv;
    o4.w = o[nb][3] * inv;
    if (drawn) {
      float4 vd4 = *reinterpret_cast<const float4*>(Vd + g);
      float4 v4  = *reinterpret_cast<const float4*>(V + g);
      o4.x += pdinv * (vd4.x - v4.x);
      o4.y += pdinv * (vd4.y - v4.y);
      o4.z += pdinv * (vd4.z - v4.z);
      o4.w += pdinv * (vd4.w - v4.w);
    }
    *reinterpret_cast<float4*>(out + g) = o4;
  }
}

extern "C" void kernel_launch(void* const* d_in, const int* in_sizes, int n_in,
                              void* d_out, int out_size, void* d_ws, size_t ws_size,
                              hipStream_t stream) {
  const float* q  = (const float*)d_in[0];
  const float* k  = (const float*)d_in[1];
  const float* v  = (const float*)d_in[2];
  const float* qd = (const float*)d_in[3];
  const float* kd = (const float*)d_in[4];
  const float* vd = (const float*)d_in[5];
  // d_in[6] = attn_mask (analytic), d_in[7] = history_len (HIST)
  float* out = (float*)d_out;

  // 1024 blocks: 64 (b,h) x 16 q-tiles — no LDS, no barriers; waves independent
  ftcca_nolds<<<dim3(1024), dim3(256), 0, stream>>>(q, k, v, qd, kd, vd, out);
}